// Round 3
// baseline (354.668 us; speedup 1.0000x reference)
//
#include <hip/hip_runtime.h>
#include <hip/hip_bf16.h>
#include <cstdint>
#include <cstddef>

typedef __bf16 bf16;
typedef __attribute__((ext_vector_type(8))) __bf16 bf16x8;
typedef __attribute__((ext_vector_type(4))) float floatx4;

#define NPIX 65536   // B*H*W

__device__ inline void async_copy16(void* lds, const void* g) {
    __builtin_amdgcn_global_load_lds(
        (const __attribute__((address_space(1))) void*)g,
        (__attribute__((address_space(3))) void*)lds, 16, 0, 0);
}

// ---------------------------------------------------------------- K0: Wfull = [Wo | Wo@Wc] (bf16), bco = Wo@bc + bo (fp32)
// r0 version (385 blocks x 384 threads): known-good, fully parallel.
__global__ void k_prep_w(const float* __restrict__ Wc, const float* __restrict__ bc,
                         const float* __restrict__ Wo, const float* __restrict__ bo,
                         bf16* __restrict__ Wfull, float* __restrict__ bco) {
    int blk = blockIdx.x;
    int t = threadIdx.x;          // 0..383
    if (blk < 384) {
        int o = blk;
        float acc = 0.f;
        for (int d = 0; d < 384; ++d)
            acc += Wo[o * 384 + d] * Wc[d * 384 + t];
        Wfull[(size_t)o * 768 + t]       = (bf16)Wo[o * 384 + t];
        Wfull[(size_t)o * 768 + 384 + t] = (bf16)acc;
    } else {
        int o = t;
        float acc = bo[o];
        for (int d = 0; d < 384; ++d)
            acc += Wo[o * 384 + d] * bc[d];
        bco[o] = acc;
    }
}

// ---------------------------------------------------------------- K1: convert + projections (E=2)
// xb is written D-MAJOR: xb[cblk][pixel][16] with cblk = d/16
__global__ void k_proj(const float* __restrict__ xf, bf16* __restrict__ xb,
                       const float* __restrict__ W1h, const float* __restrict__ b1h,
                       const float* __restrict__ W1w, const float* __restrict__ b1w,
                       float* __restrict__ yh, float* __restrict__ yw) {
    int t  = threadIdx.x;
    int lg = t & 7;                 // lane within 8-lane pixel group
    int pg = t >> 3;                // pixel group in block (0..31)
    int p  = blockIdx.x * 32 + pg;  // pixel id
    int b = p >> 10, h = (p >> 5) & 31, w = p & 31;
    const float4* xp4 = (const float4*)(xf + (size_t)p * 384);
    float a0 = 0.f, a1 = 0.f, a2 = 0.f, a3 = 0.f;
#pragma unroll
    for (int j = 0; j < 6; ++j) {
        int c = j * 8 + lg;         // 8-element chunk 0..47
        float4 xa = xp4[c * 2], xcv = xp4[c * 2 + 1];
        bf16x8 v;
        v[0] = (bf16)xa.x; v[1] = (bf16)xa.y; v[2] = (bf16)xa.z; v[3] = (bf16)xa.w;
        v[4] = (bf16)xcv.x; v[5] = (bf16)xcv.y; v[6] = (bf16)xcv.z; v[7] = (bf16)xcv.w;
        *(bf16x8*)(xb + ((size_t)(c >> 1) * NPIX + p) * 16 + (c & 1) * 8) = v;
        const float4* h0 = (const float4*)(W1h + c * 8);
        const float4* h1 = (const float4*)(W1h + 384 + c * 8);
        const float4* w0 = (const float4*)(W1w + c * 8);
        const float4* w1 = (const float4*)(W1w + 384 + c * 8);
        float4 h0a = h0[0], h0b = h0[1], h1a = h1[0], h1b = h1[1];
        float4 w0a = w0[0], w0b = w0[1], w1a = w1[0], w1b = w1[1];
        a0 += xa.x*h0a.x + xa.y*h0a.y + xa.z*h0a.z + xa.w*h0a.w
            + xcv.x*h0b.x + xcv.y*h0b.y + xcv.z*h0b.z + xcv.w*h0b.w;
        a1 += xa.x*h1a.x + xa.y*h1a.y + xa.z*h1a.z + xa.w*h1a.w
            + xcv.x*h1b.x + xcv.y*h1b.y + xcv.z*h1b.z + xcv.w*h1b.w;
        a2 += xa.x*w0a.x + xa.y*w0a.y + xa.z*w0a.z + xa.w*w0a.w
            + xcv.x*w0b.x + xcv.y*w0b.y + xcv.z*w0b.z + xcv.w*w0b.w;
        a3 += xa.x*w1a.x + xa.y*w1a.y + xa.z*w1a.z + xa.w*w1a.w
            + xcv.x*w1b.x + xcv.y*w1b.y + xcv.z*w1b.z + xcv.w*w1b.w;
    }
#pragma unroll
    for (int m = 1; m < 8; m <<= 1) {
        a0 += __shfl_xor(a0, m, 64);
        a1 += __shfl_xor(a1, m, 64);
        a2 += __shfl_xor(a2, m, 64);
        a3 += __shfl_xor(a3, m, 64);
    }
    if (lg == 0) {
        yh[((b * 2 + 0) * 32 + h) * 32 + w] = a0 + b1h[0];
        yh[((b * 2 + 1) * 32 + h) * 32 + w] = a1 + b1h[1];
        yw[((b * 2 + 0) * 32 + w) * 32 + h] = a2 + b1w[0];
        yw[((b * 2 + 1) * 32 + w) * 32 + h] = a3 + b1w[1];
    }
}

// ---------------------------------------------------------------- K2: grouped mix + softmax -> attn[b][l][r1][r2] (bf16)
// Single launch covers h (blk<2048) and w (blk>=2048) variants.
__global__ void k_attn(const float* __restrict__ yh_in, const float* __restrict__ yw_in,
                       const float* __restrict__ W2h, const float* __restrict__ b2h,
                       const float* __restrict__ W2w, const float* __restrict__ b2w,
                       bf16* __restrict__ attn_h, bf16* __restrict__ attn_w) {
    int blk = blockIdx.x;                 // 2 * B*32
    const float* yproj; const float* W2; const float* b2; bf16* attn;
    if (blk < 2048) { yproj = yh_in; W2 = W2h; b2 = b2h; attn = attn_h; }
    else            { yproj = yw_in; W2 = W2w; b2 = b2w; attn = attn_w; blk -= 2048; }
    int bi = blk >> 5, r1 = blk & 31;
    int g = r1 >> 2;
    int cb = g * 8;
    int e = cb >> 5, rb = cb & 31;        // 8 consecutive rows of plane e
    int lane = threadIdx.x;               // 64
    int l = lane & 31, half = lane >> 5;
    float yv[8];
    const float* ybase = yproj + (((bi * 2 + e) * 32 + rb) * 32 + l);
#pragma unroll
    for (int c = 0; c < 8; ++c) yv[c] = ybase[c * 32];
    float z[16];
#pragma unroll
    for (int jj = 0; jj < 16; ++jj) {
        int r2 = half * 16 + jj;
        int row = r1 * 32 + r2;
        const float4* wp = (const float4*)(W2 + (size_t)row * 8);
        float4 wa = wp[0], wb = wp[1];
        z[jj] = b2[row]
              + yv[0]*wa.x + yv[1]*wa.y + yv[2]*wa.z + yv[3]*wa.w
              + yv[4]*wb.x + yv[5]*wb.y + yv[6]*wb.z + yv[7]*wb.w;
    }
    float m = -1e30f;
#pragma unroll
    for (int jj = 0; jj < 16; ++jj) m = fmaxf(m, z[jj]);
    m = fmaxf(m, __shfl_xor(m, 32, 64));
    float s = 0.f;
#pragma unroll
    for (int jj = 0; jj < 16; ++jj) { z[jj] = __expf(z[jj] - m); s += z[jj]; }
    s += __shfl_xor(s, 32, 64);
    float inv = 1.f / s;
    bf16x8 o0, o1;
#pragma unroll
    for (int jj = 0; jj < 8; ++jj) o0[jj] = (bf16)(z[jj] * inv);
#pragma unroll
    for (int jj = 0; jj < 8; ++jj) o1[jj] = (bf16)(z[8 + jj] * inv);
    bf16x8* dst = (bf16x8*)(attn + ((((size_t)bi * 32 + l) * 32 + r1) * 32 + half * 16));
    dst[0] = o0;
    dst[1] = o1;
}

// ---------------------------------------------------------------- K3: fused Yh+Yw -> T (bf16, d-major)
__global__ __launch_bounds__(256) void k_mix(const bf16* __restrict__ x,
                                             const bf16* __restrict__ attn_h,
                                             const bf16* __restrict__ attn_w,
                                             bf16* __restrict__ T) {
    __shared__ bf16 Xs[1024 * 16];      // [pixel][16 cols]  32 KB
    __shared__ bf16 Ts[1024 * 16];      // Yh park           32 KB
    int n = blockIdx.x;                 // 0..1535
    // XCD-affine: all 24 c-slices of one image land on the same XCD (attn reuse)
    int idx = n >> 3;
    int bi = (n & 7) * 8 + idx / 24;
    int c  = idx % 24;
    int tid = threadIdx.x;
    int wv = tid >> 6, lane = tid & 63;
    int n16 = lane & 15, quad = lane >> 4;

    // ---- stage x[c][bi*1024 .. +1024][16] -> Xs (fully contiguous)
    const bf16* src = x + ((size_t)c * NPIX + bi * 1024) * 16;
#pragma unroll
    for (int it = 0; it < 8; ++it)
        async_copy16((char*)Xs + (it * 256 + tid) * 16,
                     (const char*)src + (size_t)(it * 256 + tid) * 16);
    __syncthreads();

    // ---- phase 1: Yh[h,w,d] = sum_j ah[w,h,j] x[j,w,d] -> Ts
#pragma unroll
    for (int wl = 0; wl < 8; ++wl) {
        int w = wv * 8 + wl;
        const bf16* ab = attn_h + ((size_t)(bi * 32 + w) * 32) * 32;
        bf16x8 af0 = *(const bf16x8*)(ab + n16 * 32 + quad * 8);
        bf16x8 af1 = *(const bf16x8*)(ab + (16 + n16) * 32 + quad * 8);
        bf16x8 bfrag;
#pragma unroll
        for (int i = 0; i < 8; ++i) {
            int j = quad * 8 + i;
            bfrag[i] = Xs[(j * 32 + w) * 16 + n16];
        }
        floatx4 c0 = {0.f, 0.f, 0.f, 0.f}, c1 = {0.f, 0.f, 0.f, 0.f};
        c0 = __builtin_amdgcn_mfma_f32_16x16x32_bf16(af0, bfrag, c0, 0, 0, 0);
        c1 = __builtin_amdgcn_mfma_f32_16x16x32_bf16(af1, bfrag, c1, 0, 0, 0);
#pragma unroll
        for (int rr = 0; rr < 4; ++rr) {
            int h0 = quad * 4 + rr;
            Ts[(h0 * 32 + w) * 16 + n16]        = (bf16)c0[rr];
            Ts[((16 + h0) * 32 + w) * 16 + n16] = (bf16)c1[rr];
        }
    }
    __syncthreads();

    // ---- phase 2: Yw[h,w,d] = sum_j aw[h,w,j] x[h,j,d]; Xs <- Yh + Yw
#pragma unroll
    for (int hl = 0; hl < 8; ++hl) {
        int h = wv * 8 + hl;
        const bf16* ab = attn_w + ((size_t)(bi * 32 + h) * 32) * 32;
        bf16x8 af0 = *(const bf16x8*)(ab + n16 * 32 + quad * 8);
        bf16x8 af1 = *(const bf16x8*)(ab + (16 + n16) * 32 + quad * 8);
        bf16x8 bfrag;
#pragma unroll
        for (int i = 0; i < 8; ++i) {
            int j = quad * 8 + i;
            bfrag[i] = Xs[(h * 32 + j) * 16 + n16];
        }
        floatx4 c0 = {0.f, 0.f, 0.f, 0.f}, c1 = {0.f, 0.f, 0.f, 0.f};
        c0 = __builtin_amdgcn_mfma_f32_16x16x32_bf16(af0, bfrag, c0, 0, 0, 0);
        c1 = __builtin_amdgcn_mfma_f32_16x16x32_bf16(af1, bfrag, c1, 0, 0, 0);
        // in-wave RAW only: this wave alone reads/writes rows h*32..h*32+31
#pragma unroll
        for (int rr = 0; rr < 4; ++rr) {
            int w0 = quad * 4 + rr;
            Xs[(h * 32 + w0) * 16 + n16] =
                (bf16)(c0[rr] + (float)Ts[(h * 32 + w0) * 16 + n16]);
            Xs[(h * 32 + 16 + w0) * 16 + n16] =
                (bf16)(c1[rr] + (float)Ts[(h * 32 + 16 + w0) * 16 + n16]);
        }
    }
    __syncthreads();

    // ---- contiguous vectorized block store Xs -> T[c][bi*1024..][16]
    bf16* dst = T + ((size_t)c * NPIX + bi * 1024) * 16;
#pragma unroll
    for (int it = 0; it < 8; ++it)
        *(bf16x8*)(dst + (size_t)(it * 256 + tid) * 8) =
            *(const bf16x8*)(Xs + (it * 256 + tid) * 8);
}

// ---------------------------------------------------------------- K5: out = [T|xb] @ Wfull^T + bco   (M=65536,N=384,K=768), out fp32
// A: global_load_lds double-buffer, XOR-swizzled (conflict-free, verified r2).
// B: Wfull is 590KB, L2-resident, shared by all pt-blocks -> read fragments
//    DIRECTLY from global each K-step (no LDS staging). Halves the stage insts
//    drained at the barrier and halves LDS (64->32KB => 5 blocks/CU TLP).
__global__ __launch_bounds__(256) void k_gemm(const bf16* __restrict__ T, const bf16* __restrict__ x,
                                              const bf16* __restrict__ Wfull, const float* __restrict__ bco,
                                              float* __restrict__ out) {
    __shared__ bf16 As[2][128 * 64];
    int bx = blockIdx.x;               // 0..1535
    int gid = (bx & 7) * 192 + (bx >> 3);
    int nt = gid % 3, pt = gid / 3;
    int obase = nt * 128;
    int pbase = pt * 128;
    int tid = threadIdx.x;
    int wv = tid >> 6, lane = tid & 63;
    int wm = wv & 1, wn = wv >> 1;
    int n16 = lane & 15, quad = lane >> 4;
    int srow = lane >> 3, sch = lane & 7;   // staging: 8 rows x 8 chunks per wave-inst
    int scha = sch ^ srow;                  // swizzled source chunk (row&7 == srow since r0%8==0)
    floatx4 zero = {0.f, 0.f, 0.f, 0.f};
    floatx4 acc[4][4];
#pragma unroll
    for (int i = 0; i < 4; ++i)
#pragma unroll
        for (int j = 0; j < 4; ++j) acc[i][j] = zero;

    // per-thread B row pointers (rows fixed; only the kt*64 column offset moves)
    const bf16* browp[4];
#pragma unroll
    for (int j = 0; j < 4; ++j)
        browp[j] = Wfull + (size_t)(obase + wn * 64 + j * 16 + n16) * 768 + quad * 8;

    auto stage = [&](int buf, int kt) {
        const bf16* Ag = (kt < 6) ? T : x;                 // d-major [24][NPIX][16]
        int k6 = (kt < 6) ? kt : kt - 6;
        size_t arow = ((size_t)(k6 * 4 + (scha >> 1))) * NPIX + pbase;
#pragma unroll
        for (int it = 0; it < 4; ++it) {
            int r0 = wv * 32 + it * 8;
            async_copy16((void*)(As[buf] + r0 * 64 + lane * 8),
                         (const void*)(Ag + (arow + r0 + srow) * 16 + (scha & 1) * 8));
        }
    };

    stage(0, 0);
    __syncthreads();
    int buf = 0;
    int sa = n16 & 7;                       // read-side swizzle key (row&7)
    for (int kt = 0; kt < 12; ++kt) {
        if (kt < 11) stage(buf ^ 1, kt + 1);   // async prefetch next A-tile
#pragma unroll
        for (int ks = 0; ks < 2; ++ks) {
            bf16x8 a[4], b[4];
#pragma unroll
            for (int j = 0; j < 4; ++j)
                b[j] = *(const bf16x8*)(browp[j] + kt * 64 + ks * 32);
            int coff = ((ks * 4 + quad) ^ sa) * 8;  // phys chunk = logical ^ (row&7)
#pragma unroll
            for (int i = 0; i < 4; ++i)
                a[i] = *(const bf16x8*)(As[buf] + (wm * 64 + i * 16 + n16) * 64 + coff);
#pragma unroll
            for (int i = 0; i < 4; ++i)
#pragma unroll
                for (int j = 0; j < 4; ++j)
                    acc[i][j] = __builtin_amdgcn_mfma_f32_16x16x32_bf16(a[i], b[j], acc[i][j], 0, 0, 0);
        }
        __syncthreads();                       // drains A-stage (4 insts) + LDS reads
        buf ^= 1;
    }
    // epilogue: fp32 output
#pragma unroll
    for (int j = 0; j < 4; ++j) {
        int o = obase + wn * 64 + j * 16 + n16;
        float bcv = bco[o];
#pragma unroll
        for (int i = 0; i < 4; ++i) {
            int prow = pbase + wm * 64 + i * 16 + quad * 4;
#pragma unroll
            for (int r = 0; r < 4; ++r)
                out[(size_t)(prow + r) * 384 + o] = acc[i][j][r] + bcv;
        }
    }
}

// ---------------------------------------------------------------- launch
extern "C" void kernel_launch(void* const* d_in, const int* in_sizes, int n_in,
                              void* d_out, int out_size, void* d_ws, size_t ws_size,
                              hipStream_t stream) {
    const float* x   = (const float*)d_in[0];
    const float* Wc  = (const float*)d_in[1];
    const float* bc  = (const float*)d_in[2];
    const float* Wo  = (const float*)d_in[3];
    const float* bo  = (const float*)d_in[4];
    const float* W1h = (const float*)d_in[5];
    const float* b1h = (const float*)d_in[6];
    const float* W2h = (const float*)d_in[7];
    const float* b2h = (const float*)d_in[8];
    const float* W1w = (const float*)d_in[9];
    const float* b1w = (const float*)d_in[10];
    const float* W2w = (const float*)d_in[11];
    const float* b2w = (const float*)d_in[12];
    float* out = (float*)d_out;

    char* ws = (char*)d_ws;
    size_t off = 0;
    auto alloc = [&](size_t bytes) {
        void* p = ws + off;
        off = (off + bytes + 255) & ~(size_t)255;
        return p;
    };
    bf16*  xb     = (bf16*)alloc((size_t)NPIX * 384 * 2);  // bf16 x, d-major [24][NPIX][16]
    float* yh     = (float*)alloc((size_t)131072 * 4);     // [B][2][32][32]
    float* yw     = (float*)alloc((size_t)131072 * 4);
    bf16*  attn_h = (bf16*)alloc((size_t)2097152 * 2);     // [B][W][H][H]
    bf16*  attn_w = (bf16*)alloc((size_t)2097152 * 2);     // [B][H][W][W]
    bf16*  T      = (bf16*)alloc((size_t)NPIX * 384 * 2);  // Yh+Yw, d-major [24][NPIX][16]
    bf16*  Wfull  = (bf16*)alloc((size_t)384 * 768 * 2);   // [Wo | Wo@Wc]
    float* bco    = (float*)alloc((size_t)384 * 4);

    hipLaunchKernelGGL(k_prep_w, dim3(385), dim3(384), 0, stream, Wc, bc, Wo, bo, Wfull, bco);
    hipLaunchKernelGGL(k_proj, dim3(2048), dim3(256), 0, stream, x, xb, W1h, b1h, W1w, b1w, yh, yw);
    hipLaunchKernelGGL(k_attn, dim3(4096), dim3(64), 0, stream, yh, yw, W2h, b2h, W2w, b2w, attn_h, attn_w);
    hipLaunchKernelGGL(k_mix, dim3(1536), dim3(256), 0, stream, xb, attn_h, attn_w, T);
    hipLaunchKernelGGL(k_gemm, dim3(1536), dim3(256), 0, stream, T, xb, Wfull, bco, out);
}

// Round 4
// 320.954 us; speedup vs baseline: 1.1050x; 1.1050x over previous
//
#include <hip/hip_runtime.h>
#include <hip/hip_bf16.h>
#include <cstdint>
#include <cstddef>

typedef __bf16 bf16;
typedef __attribute__((ext_vector_type(8))) __bf16 bf16x8;
typedef __attribute__((ext_vector_type(4))) float floatx4;

#define NPIX 65536   // B*H*W

__device__ inline void async_copy16(void* lds, const void* g) {
    __builtin_amdgcn_global_load_lds(
        (const __attribute__((address_space(1))) void*)g,
        (__attribute__((address_space(3))) void*)lds, 16, 0, 0);
}

// ---------------------------------------------------------------- K0: Wfull = [Wo | Wo@Wc] (bf16), bco = Wo@bc + bo (fp32)
__global__ void k_prep_w(const float* __restrict__ Wc, const float* __restrict__ bc,
                         const float* __restrict__ Wo, const float* __restrict__ bo,
                         bf16* __restrict__ Wfull, float* __restrict__ bco) {
    int blk = blockIdx.x;
    int t = threadIdx.x;          // 0..383
    if (blk < 384) {
        int o = blk;
        float acc = 0.f;
        for (int d = 0; d < 384; ++d)
            acc += Wo[o * 384 + d] * Wc[d * 384 + t];
        Wfull[(size_t)o * 768 + t]       = (bf16)Wo[o * 384 + t];
        Wfull[(size_t)o * 768 + 384 + t] = (bf16)acc;
    } else {
        int o = t;
        float acc = bo[o];
        for (int d = 0; d < 384; ++d)
            acc += Wo[o * 384 + d] * bc[d];
        bco[o] = acc;
    }
}

// ---------------------------------------------------------------- K1: convert + projections (E=2), xb row-major [pixel][384]
__global__ void k_proj(const float* __restrict__ xf, bf16* __restrict__ xb,
                       const float* __restrict__ W1h, const float* __restrict__ b1h,
                       const float* __restrict__ W1w, const float* __restrict__ b1w,
                       float* __restrict__ yh, float* __restrict__ yw) {
    int t  = threadIdx.x;
    int lg = t & 7;                 // lane within 8-lane pixel group
    int pg = t >> 3;                // pixel group in block (0..31)
    int p  = blockIdx.x * 32 + pg;  // pixel id
    int b = p >> 10, h = (p >> 5) & 31, w = p & 31;
    const float4* xp4 = (const float4*)(xf + (size_t)p * 384);
    float a0 = 0.f, a1 = 0.f, a2 = 0.f, a3 = 0.f;
#pragma unroll
    for (int j = 0; j < 6; ++j) {
        int c = j * 8 + lg;         // 8-element chunk 0..47
        float4 xa = xp4[c * 2], xcv = xp4[c * 2 + 1];
        bf16x8 v;
        v[0] = (bf16)xa.x; v[1] = (bf16)xa.y; v[2] = (bf16)xa.z; v[3] = (bf16)xa.w;
        v[4] = (bf16)xcv.x; v[5] = (bf16)xcv.y; v[6] = (bf16)xcv.z; v[7] = (bf16)xcv.w;
        *(bf16x8*)(xb + (size_t)p * 384 + c * 8) = v;
        const float4* h0 = (const float4*)(W1h + c * 8);
        const float4* h1 = (const float4*)(W1h + 384 + c * 8);
        const float4* w0 = (const float4*)(W1w + c * 8);
        const float4* w1 = (const float4*)(W1w + 384 + c * 8);
        float4 h0a = h0[0], h0b = h0[1], h1a = h1[0], h1b = h1[1];
        float4 w0a = w0[0], w0b = w0[1], w1a = w1[0], w1b = w1[1];
        a0 += xa.x*h0a.x + xa.y*h0a.y + xa.z*h0a.z + xa.w*h0a.w
            + xcv.x*h0b.x + xcv.y*h0b.y + xcv.z*h0b.z + xcv.w*h0b.w;
        a1 += xa.x*h1a.x + xa.y*h1a.y + xa.z*h1a.z + xa.w*h1a.w
            + xcv.x*h1b.x + xcv.y*h1b.y + xcv.z*h1b.z + xcv.w*h1b.w;
        a2 += xa.x*w0a.x + xa.y*w0a.y + xa.z*w0a.z + xa.w*w0a.w
            + xcv.x*w0b.x + xcv.y*w0b.y + xcv.z*w0b.z + xcv.w*w0b.w;
        a3 += xa.x*w1a.x + xa.y*w1a.y + xa.z*w1a.z + xa.w*w1a.w
            + xcv.x*w1b.x + xcv.y*w1b.y + xcv.z*w1b.z + xcv.w*w1b.w;
    }
#pragma unroll
    for (int m = 1; m < 8; m <<= 1) {
        a0 += __shfl_xor(a0, m, 64);
        a1 += __shfl_xor(a1, m, 64);
        a2 += __shfl_xor(a2, m, 64);
        a3 += __shfl_xor(a3, m, 64);
    }
    if (lg == 0) {
        yh[((b * 2 + 0) * 32 + h) * 32 + w] = a0 + b1h[0];
        yh[((b * 2 + 1) * 32 + h) * 32 + w] = a1 + b1h[1];
        yw[((b * 2 + 0) * 32 + w) * 32 + h] = a2 + b1w[0];
        yw[((b * 2 + 1) * 32 + w) * 32 + h] = a3 + b1w[1];
    }
}

// ---------------------------------------------------------------- K2: grouped mix + softmax -> attn[b][l][r1][r2] (bf16)
// Single launch covers h (blk<2048) and w (blk>=2048) variants.
__global__ void k_attn(const float* __restrict__ yh_in, const float* __restrict__ yw_in,
                       const float* __restrict__ W2h, const float* __restrict__ b2h,
                       const float* __restrict__ W2w, const float* __restrict__ b2w,
                       bf16* __restrict__ attn_h, bf16* __restrict__ attn_w) {
    int blk = blockIdx.x;                 // 2 * B*32
    const float* yproj; const float* W2; const float* b2; bf16* attn;
    if (blk < 2048) { yproj = yh_in; W2 = W2h; b2 = b2h; attn = attn_h; }
    else            { yproj = yw_in; W2 = W2w; b2 = b2w; attn = attn_w; blk -= 2048; }
    int bi = blk >> 5, r1 = blk & 31;
    int g = r1 >> 2;
    int cb = g * 8;
    int e = cb >> 5, rb = cb & 31;        // 8 consecutive rows of plane e
    int lane = threadIdx.x;               // 64
    int l = lane & 31, half = lane >> 5;
    float yv[8];
    const float* ybase = yproj + (((bi * 2 + e) * 32 + rb) * 32 + l);
#pragma unroll
    for (int c = 0; c < 8; ++c) yv[c] = ybase[c * 32];
    float z[16];
#pragma unroll
    for (int jj = 0; jj < 16; ++jj) {
        int r2 = half * 16 + jj;
        int row = r1 * 32 + r2;
        const float4* wp = (const float4*)(W2 + (size_t)row * 8);
        float4 wa = wp[0], wb = wp[1];
        z[jj] = b2[row]
              + yv[0]*wa.x + yv[1]*wa.y + yv[2]*wa.z + yv[3]*wa.w
              + yv[4]*wb.x + yv[5]*wb.y + yv[6]*wb.z + yv[7]*wb.w;
    }
    float m = -1e30f;
#pragma unroll
    for (int jj = 0; jj < 16; ++jj) m = fmaxf(m, z[jj]);
    m = fmaxf(m, __shfl_xor(m, 32, 64));
    float s = 0.f;
#pragma unroll
    for (int jj = 0; jj < 16; ++jj) { z[jj] = __expf(z[jj] - m); s += z[jj]; }
    s += __shfl_xor(s, 32, 64);
    float inv = 1.f / s;
    bf16x8 o0, o1;
#pragma unroll
    for (int jj = 0; jj < 8; ++jj) o0[jj] = (bf16)(z[jj] * inv);
#pragma unroll
    for (int jj = 0; jj < 8; ++jj) o1[jj] = (bf16)(z[8 + jj] * inv);
    bf16x8* dst = (bf16x8*)(attn + ((((size_t)bi * 32 + l) * 32 + r1) * 32 + half * 16));
    dst[0] = o0;
    dst[1] = o1;
}

// ---------------------------------------------------------------- K3: fused Yh+Yw -> T (bf16, row-major) — r0 proven version
__global__ __launch_bounds__(256) void k_mix(const bf16* __restrict__ x,
                                             const bf16* __restrict__ attn_h,
                                             const bf16* __restrict__ attn_w,
                                             bf16* __restrict__ T) {
    __shared__ bf16 Xs[1024 * 16];      // [pixel][16 cols]  32 KB
    __shared__ bf16 Ts[1024 * 16];      // Yh park           32 KB
    int n = blockIdx.x;                 // 0..1535
    int a = n >> 5, r = n & 31;
    int q = a * 8 + (r & 7);            // 0..383
    int bi = q / 6, cq = q % 6;
    int c = cq * 4 + (r >> 3);          // 0..23
    int dbase = c * 16;
    int tid = threadIdx.x;
    int wv = tid >> 6, lane = tid & 63;
    int n16 = lane & 15, quad = lane >> 4;

    // ---- stage x[bi][:, dbase:dbase+16] -> Xs (lane-linear 16B chunks)
    const char* gbase = (const char*)(x + (size_t)bi * 1024 * 384 + dbase);
#pragma unroll
    for (int it = 0; it < 8; ++it) {
        int p0 = wv * 256 + it * 32;                 // 32 pixels per inst
        const char* g = gbase + (size_t)(p0 + (lane >> 1)) * 768 + (lane & 1) * 16;
        char* l = (char*)Xs + p0 * 32 + lane * 16;
        async_copy16(l, g);
    }
    __syncthreads();

    // ---- phase 1: Yh[h,w,d] = sum_j ah[w,h,j] x[j,w,d] -> Ts
#pragma unroll
    for (int wl = 0; wl < 8; ++wl) {
        int w = wv * 8 + wl;
        const bf16* ab = attn_h + ((size_t)(bi * 32 + w) * 32) * 32;
        bf16x8 af0 = *(const bf16x8*)(ab + n16 * 32 + quad * 8);
        bf16x8 af1 = *(const bf16x8*)(ab + (16 + n16) * 32 + quad * 8);
        bf16x8 bfrag;
#pragma unroll
        for (int i = 0; i < 8; ++i) {
            int j = quad * 8 + i;
            bfrag[i] = Xs[(j * 32 + w) * 16 + n16];
        }
        floatx4 c0 = {0.f, 0.f, 0.f, 0.f}, c1 = {0.f, 0.f, 0.f, 0.f};
        c0 = __builtin_amdgcn_mfma_f32_16x16x32_bf16(af0, bfrag, c0, 0, 0, 0);
        c1 = __builtin_amdgcn_mfma_f32_16x16x32_bf16(af1, bfrag, c1, 0, 0, 0);
#pragma unroll
        for (int rr = 0; rr < 4; ++rr) {
            int h0 = quad * 4 + rr;
            Ts[(h0 * 32 + w) * 16 + n16]        = (bf16)c0[rr];
            Ts[((16 + h0) * 32 + w) * 16 + n16] = (bf16)c1[rr];
        }
    }
    __syncthreads();

    // ---- phase 2: Yw[h,w,d] = sum_j aw[h,w,j] x[h,j,d]; T = Yh + Yw
#pragma unroll
    for (int hl = 0; hl < 8; ++hl) {
        int h = wv * 8 + hl;
        const bf16* ab = attn_w + ((size_t)(bi * 32 + h) * 32) * 32;
        bf16x8 af0 = *(const bf16x8*)(ab + n16 * 32 + quad * 8);
        bf16x8 af1 = *(const bf16x8*)(ab + (16 + n16) * 32 + quad * 8);
        bf16x8 bfrag;
#pragma unroll
        for (int i = 0; i < 8; ++i) {
            int j = quad * 8 + i;
            bfrag[i] = Xs[(h * 32 + j) * 16 + n16];
        }
        floatx4 c0 = {0.f, 0.f, 0.f, 0.f}, c1 = {0.f, 0.f, 0.f, 0.f};
        c0 = __builtin_amdgcn_mfma_f32_16x16x32_bf16(af0, bfrag, c0, 0, 0, 0);
        c1 = __builtin_amdgcn_mfma_f32_16x16x32_bf16(af1, bfrag, c1, 0, 0, 0);
        bf16* Tr = T + ((size_t)(bi * 32 + h) * 32) * 384 + dbase;
#pragma unroll
        for (int rr = 0; rr < 4; ++rr) {
            int w0 = quad * 4 + rr;
            Tr[(size_t)w0 * 384 + n16] =
                (bf16)(c0[rr] + (float)Ts[(h * 32 + w0) * 16 + n16]);
            Tr[(size_t)(16 + w0) * 384 + n16] =
                (bf16)(c1[rr] + (float)Ts[(h * 32 + 16 + w0) * 16 + n16]);
        }
    }
}

// ---------------------------------------------------------------- K5: out = [T|xb] @ Wfull^T + bco   (M=65536,N=384,K=768), out fp32
// r0 proven structure (reg-staged, LDP=72 padded LDS, 2 barriers/K-step)
// + T14 issue-early/write-late: loads for kt+1 are ISSUED after tile kt is in
//   LDS, and CONSUMED (ds_write) only after kt's 32-MFMA section — the global
//   load latency hides under the MFMAs instead of stalling the next ds_write.
#define LDP 72
__global__ __launch_bounds__(256) void k_gemm(const bf16* __restrict__ T, const bf16* __restrict__ x,
                                              const bf16* __restrict__ Wfull, const float* __restrict__ bco,
                                              float* __restrict__ out) {
    __shared__ bf16 As[128 * LDP];
    __shared__ bf16 Bs[128 * LDP];
    int bx = blockIdx.x;               // 0..1535
    int gid = (bx & 7) * 192 + (bx >> 3);
    int nt = gid % 3, pt = gid / 3;
    int obase = nt * 128;
    int pbase = pt * 128;
    int tid = threadIdx.x;
    int wv = tid >> 6, lane = tid & 63;
    int wm = wv & 1, wn = wv >> 1;
    int n16 = lane & 15, quad = lane >> 4;
    int lrow = tid >> 3;           // 0..31
    int lchunk = tid & 7;          // 0..7
    floatx4 zero = {0.f, 0.f, 0.f, 0.f};
    floatx4 acc[4][4];
#pragma unroll
    for (int i = 0; i < 4; ++i)
#pragma unroll
        for (int j = 0; j < 4; ++j) acc[i][j] = zero;

    const bf16* Bg0 = Wfull + (size_t)obase * 768;

    auto load_tile = [&](int kt, bf16x8 (&av)[4], bf16x8 (&bv)[4]) {
        const bf16* Asrc = (kt < 6) ? (T + (size_t)pbase * 384 + kt * 64)
                                    : (x + (size_t)pbase * 384 + (kt - 6) * 64);
        const bf16* Bsrc = Bg0 + kt * 64;
#pragma unroll
        for (int s = 0; s < 4; ++s)
            av[s] = *(const bf16x8*)(Asrc + (size_t)(s * 32 + lrow) * 384 + lchunk * 8);
#pragma unroll
        for (int s = 0; s < 4; ++s)
            bv[s] = *(const bf16x8*)(Bsrc + (size_t)(s * 32 + lrow) * 768 + lchunk * 8);
    };

    auto step = [&](int kt, bf16x8 (&av)[4], bf16x8 (&bv)[4],
                    bf16x8 (&nav)[4], bf16x8 (&nbv)[4]) {
        __syncthreads();           // previous iteration's LDS reads done
#pragma unroll
        for (int s = 0; s < 4; ++s)
            *(bf16x8*)(As + (s * 32 + lrow) * LDP + lchunk * 8) = av[s];
#pragma unroll
        for (int s = 0; s < 4; ++s)
            *(bf16x8*)(Bs + (s * 32 + lrow) * LDP + lchunk * 8) = bv[s];
        __syncthreads();
        if (kt < 11) load_tile(kt + 1, nav, nbv);   // issue; consumed next step
#pragma unroll
        for (int ks = 0; ks < 2; ++ks) {
            bf16x8 a[4], b[4];
#pragma unroll
            for (int i = 0; i < 4; ++i)
                a[i] = *(const bf16x8*)(As + (wm * 64 + i * 16 + n16) * LDP + ks * 32 + quad * 8);
#pragma unroll
            for (int i = 0; i < 4; ++i)
                b[i] = *(const bf16x8*)(Bs + (wn * 64 + i * 16 + n16) * LDP + ks * 32 + quad * 8);
#pragma unroll
            for (int i = 0; i < 4; ++i)
#pragma unroll
                for (int j = 0; j < 4; ++j)
                    acc[i][j] = __builtin_amdgcn_mfma_f32_16x16x32_bf16(a[i], b[j], acc[i][j], 0, 0, 0);
        }
    };

    bf16x8 avA[4], bvA[4], avB[4], bvB[4];
    load_tile(0, avA, bvA);
    for (int kt = 0; kt < 12; kt += 2) {
        step(kt,     avA, bvA, avB, bvB);
        step(kt + 1, avB, bvB, avA, bvA);
    }

    // epilogue: fp32 output
#pragma unroll
    for (int j = 0; j < 4; ++j) {
        int o = obase + wn * 64 + j * 16 + n16;
        float bcv = bco[o];
#pragma unroll
        for (int i = 0; i < 4; ++i) {
            int prow = pbase + wm * 64 + i * 16 + quad * 4;
#pragma unroll
            for (int r = 0; r < 4; ++r)
                out[(size_t)(prow + r) * 384 + o] = acc[i][j][r] + bcv;
        }
    }
}

// ---------------------------------------------------------------- launch
extern "C" void kernel_launch(void* const* d_in, const int* in_sizes, int n_in,
                              void* d_out, int out_size, void* d_ws, size_t ws_size,
                              hipStream_t stream) {
    const float* x   = (const float*)d_in[0];
    const float* Wc  = (const float*)d_in[1];
    const float* bc  = (const float*)d_in[2];
    const float* Wo  = (const float*)d_in[3];
    const float* bo  = (const float*)d_in[4];
    const float* W1h = (const float*)d_in[5];
    const float* b1h = (const float*)d_in[6];
    const float* W2h = (const float*)d_in[7];
    const float* b2h = (const float*)d_in[8];
    const float* W1w = (const float*)d_in[9];
    const float* b1w = (const float*)d_in[10];
    const float* W2w = (const float*)d_in[11];
    const float* b2w = (const float*)d_in[12];
    float* out = (float*)d_out;

    char* ws = (char*)d_ws;
    size_t off = 0;
    auto alloc = [&](size_t bytes) {
        void* p = ws + off;
        off = (off + bytes + 255) & ~(size_t)255;
        return p;
    };
    bf16*  xb     = (bf16*)alloc((size_t)NPIX * 384 * 2);  // bf16 copy of x, row-major
    float* yh     = (float*)alloc((size_t)131072 * 4);     // [B][2][32][32]
    float* yw     = (float*)alloc((size_t)131072 * 4);
    bf16*  attn_h = (bf16*)alloc((size_t)2097152 * 2);     // [B][W][H][H]
    bf16*  attn_w = (bf16*)alloc((size_t)2097152 * 2);     // [B][H][W][W]
    bf16*  T      = (bf16*)alloc((size_t)NPIX * 384 * 2);  // Yh+Yw, row-major
    bf16*  Wfull  = (bf16*)alloc((size_t)384 * 768 * 2);   // [Wo | Wo@Wc]
    float* bco    = (float*)alloc((size_t)384 * 4);

    hipLaunchKernelGGL(k_prep_w, dim3(385), dim3(384), 0, stream, Wc, bc, Wo, bo, Wfull, bco);
    hipLaunchKernelGGL(k_proj, dim3(2048), dim3(256), 0, stream, x, xb, W1h, b1h, W1w, b1w, yh, yw);
    hipLaunchKernelGGL(k_attn, dim3(4096), dim3(64), 0, stream, yh, yw, W2h, b2h, W2w, b2w, attn_h, attn_w);
    hipLaunchKernelGGL(k_mix, dim3(1536), dim3(256), 0, stream, xb, attn_h, attn_w, T);
    hipLaunchKernelGGL(k_gemm, dim3(1536), dim3(256), 0, stream, T, xb, Wfull, bco, out);
}